// Round 2
// baseline (303.539 us; speedup 1.0000x reference)
//
#include <hip/hip_runtime.h>
#include <hip/hip_bf16.h>

// GDGCN: out[b,c,m,t] = sum_n softmax_row(relu(t1 nv2^T))[n,m] * x[b,c,n,t]
// t1 = nv1 @ (sum_d tv[d] k[d,:,:]);  N=8192, D=32, cols = B*C*T = 192.
// Flash-style fused: adjacency never materialized; E tiles live in LDS.

#define NN 8192
#define DD 32
#define TT 12

typedef __attribute__((ext_vector_type(8))) short bf16x8;
typedef __attribute__((ext_vector_type(4))) short bf16x4;
typedef __attribute__((ext_vector_type(4))) float f32x4;

static __device__ __forceinline__ unsigned short f2bf(float f) {
  unsigned int u = __float_as_uint(f);
  u = (u + 0x7FFFu + ((u >> 16) & 1u)) >> 16;  // RNE bf16
  return (unsigned short)u;
}

// ---- fused: core = tv.k ; t1 = nv1@core (bf16) ; nv2 -> bf16 ----
__global__ __launch_bounds__(256) void k_prep(const float* __restrict__ nv1,
                                              const float* __restrict__ nv2,
                                              const float* __restrict__ timevec,
                                              const float* __restrict__ kk,
                                              const int* __restrict__ tind,
                                              unsigned short* __restrict__ t1b,
                                              unsigned short* __restrict__ nv2b) {
  __shared__ float cs[1024];
  const int tid = threadIdx.x;
  const float* tv = timevec + (size_t)tind[0] * DD;
  for (int idx = tid; idx < 1024; idx += 256) {
    float acc = 0.f;
#pragma unroll
    for (int d = 0; d < DD; ++d) acc += tv[d] * kk[d * 1024 + idx];
    cs[idx] = acc;
  }
  __syncthreads();
  const int nbase = blockIdx.x * 128;
  const int f = tid & 31, sub = tid >> 5;
#pragma unroll 4
  for (int it = 0; it < 16; ++it) {
    const int n = nbase + it * 8 + sub;
    const float* nr = nv1 + (size_t)n * DD;
    float acc = 0.f;
#pragma unroll
    for (int e = 0; e < DD; ++e) acc += nr[e] * cs[e * DD + f];
    t1b[(size_t)n * DD + f] = f2bf(acc);
  }
#pragma unroll 4
  for (int it = 0; it < 16; ++it) {
    const int idx = nbase * DD + it * 256 + tid;
    nv2b[idx] = f2bf(nv2[idx]);
  }
}

// ---- sums[n] += sum_m exp(relu(t1[n].nv2[m]))  (m-split, ILP-4 MFMA) ----
__global__ __launch_bounds__(256) void k_stats(const unsigned short* __restrict__ t1b,
                                               const unsigned short* __restrict__ nv2b,
                                               float* __restrict__ sums) {
  const int tid = threadIdx.x;
  const int w = tid >> 6, lane = tid & 63, q = lane >> 4, i16 = lane & 15;
  const int nbase = blockIdx.x * 64 + w * 16;
  // A[n-local=i16][k=q*8+j] = t1[nbase+i16][k]
  bf16x8 a = *(const bf16x8*)(t1b + (size_t)(nbase + i16) * DD + q * 8);
  const f32x4 z4 = {0.f, 0.f, 0.f, 0.f};
  float s[4] = {0.f, 0.f, 0.f, 0.f};
  const int m0 = blockIdx.y * 2048;
  for (int mt = m0; mt < m0 + 2048; mt += 64) {
#pragma unroll
    for (int u = 0; u < 4; ++u) {
      // B[k][m-local=i16] = nv2[mt+u*16+i16][k]
      bf16x8 b = *(const bf16x8*)(nv2b + (size_t)(mt + u * 16 + i16) * DD + q * 8);
      f32x4 d = __builtin_amdgcn_mfma_f32_16x16x32_bf16(a, b, z4, 0, 0, 0);
      // lane holds rows n-local = q*4+r, col m = mt+u*16+i16
#pragma unroll
      for (int r = 0; r < 4; ++r) s[r] += __expf(fmaxf(d[r], 0.f));
    }
  }
#pragma unroll
  for (int r = 0; r < 4; ++r)
    for (int off = 1; off < 16; off <<= 1) s[r] += __shfl_xor(s[r], off, 64);
  if (i16 == 0) {
#pragma unroll
    for (int r = 0; r < 4; ++r) atomicAdd(&sums[nbase + q * 4 + r], s[r]);
  }
}

// ---- yT[c][n] = bf16(x[bc][n][t] / sums[n]),  c = bc*12 + t ----
__global__ __launch_bounds__(256) void k_y(const float* __restrict__ x,
                                           const float* __restrict__ sums,
                                           unsigned short* __restrict__ yT) {
  const int n = blockIdx.x * 256 + threadIdx.x;
  const int c = blockIdx.y;
  const int bc = c / TT, t = c - bc * TT;
  float v = x[((size_t)bc * NN + n) * TT + t] / sums[n];
  yT[(size_t)c * NN + n] = f2bf(v);
}

// ---- main: out^T[col][m] += sum_n y[col][n] * E[n][m] ----
// grid (256 m-tiles of 32, ksplit 4); block 4 waves.
// Per 64-n iter: wave w computes logits D[n][m] for nsub=w (x2 msub), writes
// Et[m][n] via ds_write_b64, ONE barrier (double-buffered), then 12 accum MFMAs.
__global__ __launch_bounds__(256, 4) void k_main(const unsigned short* __restrict__ t1b,
                                                 const unsigned short* __restrict__ nv2b,
                                                 const unsigned short* __restrict__ yT,
                                                 float* __restrict__ out) {
  const int tid = threadIdx.x;
  const int w = tid >> 6, lane = tid & 63, q = lane >> 4, i16 = lane & 15;
  const int mblock = blockIdx.x * 32;
  const int nt0 = blockIdx.y * 2048;

  __shared__ unsigned short Et[2][32][72];  // [buf][m 0..31][n 0..63 +pad8]

  // logit B-frags (loop-invariant): B[k][m=i16] = nv2[mblock+ms*16+i16][k]
  bf16x8 b_nv2_0 = *(const bf16x8*)(nv2b + (size_t)(mblock + i16) * DD + q * 8);
  bf16x8 b_nv2_1 = *(const bf16x8*)(nv2b + (size_t)(mblock + 16 + i16) * DD + q * 8);

  f32x4 acc[2][3];
#pragma unroll
  for (int a = 0; a < 2; ++a)
#pragma unroll
    for (int b = 0; b < 3; ++b) acc[a][b] = (f32x4){0.f, 0.f, 0.f, 0.f};
  const f32x4 z4 = {0.f, 0.f, 0.f, 0.f};

  int p = 0;
  for (int nt = nt0; nt < nt0 + 2048; nt += 64, p ^= 1) {
    // y A-frags for this iter, issued early: A[col=i16][k=n] contiguous b128
    bf16x8 yfr[3][2];
#pragma unroll
    for (int ctl = 0; ctl < 3; ++ctl) {
      const int ct = w * 3 + ctl;
#pragma unroll
      for (int nc = 0; nc < 2; ++nc)
        yfr[ctl][nc] = *(const bf16x8*)(yT + (size_t)(ct * 16 + i16) * NN + nt + nc * 32 + q * 8);
    }
    // logits: D[n][m], wave w covers n-local w*16..w*16+15, m-local 0..31
    bf16x8 a_t1 = *(const bf16x8*)(t1b + (size_t)(nt + w * 16 + i16) * DD + q * 8);
    f32x4 d0 = __builtin_amdgcn_mfma_f32_16x16x32_bf16(a_t1, b_nv2_0, z4, 0, 0, 0);
    f32x4 d1 = __builtin_amdgcn_mfma_f32_16x16x32_bf16(a_t1, b_nv2_1, z4, 0, 0, 0);
    // lane holds n-local = w*16 + q*4 + r, m-local = i16 (d0) / 16+i16 (d1)
    bf16x4 e0, e1;
#pragma unroll
    for (int r = 0; r < 4; ++r) {
      e0[r] = (short)f2bf(__expf(fmaxf(d0[r], 0.f)));
      e1[r] = (short)f2bf(__expf(fmaxf(d1[r], 0.f)));
    }
    *(bf16x4*)&Et[p][i16][w * 16 + q * 4] = e0;       // ds_write_b64, conflict-free
    *(bf16x4*)&Et[p][16 + i16][w * 16 + q * 4] = e1;
    __syncthreads();  // single barrier: Et[p] ready; Et[p^1] free for next iter
    // accum B-frags: B[k=n][m=i16] = Et[ms*16+i16][nc*32+q*8 ..+7]  (b128)
    bf16x8 bfr[2][2];
#pragma unroll
    for (int ms = 0; ms < 2; ++ms)
#pragma unroll
      for (int nc = 0; nc < 2; ++nc)
        bfr[ms][nc] = *(const bf16x8*)&Et[p][ms * 16 + i16][nc * 32 + q * 8];
#pragma unroll
    for (int ctl = 0; ctl < 3; ++ctl)
#pragma unroll
      for (int ms = 0; ms < 2; ++ms)
#pragma unroll
        for (int nc = 0; nc < 2; ++nc)
          acc[ms][ctl] = __builtin_amdgcn_mfma_f32_16x16x32_bf16(yfr[ctl][nc], bfr[ms][nc],
                                                                 acc[ms][ctl], 0, 0, 0);
  }

  // epilogue: lane holds col = (3w+ctl)*16 + q*4 + r, m = mblock + ms*16 + i16
#pragma unroll
  for (int ms = 0; ms < 2; ++ms)
#pragma unroll
    for (int ctl = 0; ctl < 3; ++ctl) {
      const int colbase = (w * 3 + ctl) * 16 + q * 4;
      const int m = mblock + ms * 16 + i16;
#pragma unroll
      for (int r = 0; r < 4; ++r) {
        const int col = colbase + r;
        const int bc = col / TT, t = col - bc * TT;
        atomicAdd(&out[((size_t)bc * NN + m) * TT + t], acc[ms][ctl][r]);
      }
    }
}

extern "C" void kernel_launch(void* const* d_in, const int* in_sizes, int n_in,
                              void* d_out, int out_size, void* d_ws, size_t ws_size,
                              hipStream_t stream) {
  const float* x = (const float*)d_in[0];
  const float* nv1 = (const float*)d_in[1];
  const float* nv2 = (const float*)d_in[2];
  const float* tv = (const float*)d_in[3];
  const float* kk = (const float*)d_in[4];
  const int* tind = (const int*)d_in[5];
  float* out = (float*)d_out;

  char* ws = (char*)d_ws;
  unsigned short* t1b  = (unsigned short*)(ws);            //  524288 B
  unsigned short* nv2b = (unsigned short*)(ws + 524288);   //  524288 B
  float* sums          = (float*)(ws + 1048576);           //   32768 B
  unsigned short* yT   = (unsigned short*)(ws + 1081344);  // 3145728 B (end ~4.03 MB)

  hipMemsetAsync(d_out, 0, (size_t)out_size * sizeof(float), stream);
  hipMemsetAsync(sums, 0, NN * sizeof(float), stream);
  k_prep<<<64, 256, 0, stream>>>(nv1, nv2, tv, kk, tind, t1b, nv2b);
  k_stats<<<dim3(128, 4), 256, 0, stream>>>(t1b, nv2b, sums);
  k_y<<<dim3(32, 192), 256, 0, stream>>>(x, sums, yT);
  k_main<<<dim3(256, 4), 256, 0, stream>>>(t1b, nv2b, yT, out);
}

// Round 3
// 231.362 us; speedup vs baseline: 1.3120x; 1.3120x over previous
//
#include <hip/hip_runtime.h>
#include <hip/hip_bf16.h>

// GDGCN: out[b,c,m,t] = sum_n softmax_row(relu(t1 nv2^T))[n,m] * x[b,c,n,t]
// t1 = nv1 @ (sum_d tv[d] k[d,:,:]);  N=8192, D=32, cols = B*C*T = 192.
// Strategy: MATERIALIZE E^T = exp(relu(logits)) as Et[m][n] bf16 (128 MB, L3-
// resident), so the main GEMM reads BOTH operands straight from global with
// b128 loads — no LDS, no barriers, no atomics in any hot loop.

#define NN 8192
#define DD 32
#define TT 12
#define NSPLIT 8

typedef __attribute__((ext_vector_type(8))) short bf16x8;
typedef __attribute__((ext_vector_type(4))) short bf16x4;
typedef __attribute__((ext_vector_type(4))) float f32x4;

static __device__ __forceinline__ unsigned short f2bf(float f) {
  unsigned int u = __float_as_uint(f);
  u = (u + 0x7FFFu + ((u >> 16) & 1u)) >> 16;  // RNE bf16
  return (unsigned short)u;
}

// ---- fused: core = tv.k ; t1 = nv1@core (bf16) ; nv2 -> bf16 ----
__global__ __launch_bounds__(256) void k_prep(const float* __restrict__ nv1,
                                              const float* __restrict__ nv2,
                                              const float* __restrict__ timevec,
                                              const float* __restrict__ kk,
                                              const int* __restrict__ tind,
                                              unsigned short* __restrict__ t1b,
                                              unsigned short* __restrict__ nv2b) {
  __shared__ float cs[1024];
  const int tid = threadIdx.x;
  const float* tv = timevec + (size_t)tind[0] * DD;
  for (int idx = tid; idx < 1024; idx += 256) {
    float acc = 0.f;
#pragma unroll
    for (int d = 0; d < DD; ++d) acc += tv[d] * kk[d * 1024 + idx];
    cs[idx] = acc;
  }
  __syncthreads();
  const int nbase = blockIdx.x * 128;
  const int f = tid & 31, sub = tid >> 5;
#pragma unroll 4
  for (int it = 0; it < 16; ++it) {
    const int n = nbase + it * 8 + sub;
    const float* nr = nv1 + (size_t)n * DD;
    float acc = 0.f;
#pragma unroll
    for (int e = 0; e < DD; ++e) acc += nr[e] * cs[e * DD + f];
    t1b[(size_t)n * DD + f] = f2bf(acc);
  }
#pragma unroll 4
  for (int it = 0; it < 16; ++it) {
    const int idx = nbase * DD + it * 256 + tid;
    nv2b[idx] = f2bf(nv2[idx]);
  }
}

// ---- pass A: Et[m][n] = bf16(exp(relu(t1[n].nv2[m]))), sums[n] += row sums ----
// grid (128 n-strips of 64, 4 m-chunks of 2048); 4 waves; wave = 16 n x m-stream.
// No LDS, no barriers; 1 MFMA + 1 b64 store per iter; write-BW-bound.
__global__ __launch_bounds__(256) void k_passA(const unsigned short* __restrict__ t1b,
                                               const unsigned short* __restrict__ nv2b,
                                               unsigned short* __restrict__ Et,
                                               float* __restrict__ sums) {
  const int tid = threadIdx.x;
  const int w = tid >> 6, lane = tid & 63, q = lane >> 4, i16 = lane & 15;
  const int nbase = blockIdx.x * 64 + w * 16;
  const int m0 = blockIdx.y * 2048;
  // A[n-local=i16][k=q*8+j] = t1[nbase+i16][k]
  bf16x8 a = *(const bf16x8*)(t1b + (size_t)(nbase + i16) * DD + q * 8);
  const f32x4 z4 = {0.f, 0.f, 0.f, 0.f};
  float s0 = 0.f, s1 = 0.f, s2 = 0.f, s3 = 0.f;
  const int nofs = nbase + q * 4;
#pragma unroll 4
  for (int mt = m0; mt < m0 + 2048; mt += 16) {
    // B[k][m-local=i16] = nv2[mt+i16][k]
    bf16x8 b = *(const bf16x8*)(nv2b + (size_t)(mt + i16) * DD + q * 8);
    f32x4 d = __builtin_amdgcn_mfma_f32_16x16x32_bf16(a, b, z4, 0, 0, 0);
    // lane holds D[n-local=q*4+r][m = mt+i16]
    float e0 = __expf(fmaxf(d[0], 0.f));
    float e1 = __expf(fmaxf(d[1], 0.f));
    float e2 = __expf(fmaxf(d[2], 0.f));
    float e3 = __expf(fmaxf(d[3], 0.f));
    s0 += e0; s1 += e1; s2 += e2; s3 += e3;
    bf16x4 ev;
    ev[0] = (short)f2bf(e0); ev[1] = (short)f2bf(e1);
    ev[2] = (short)f2bf(e2); ev[3] = (short)f2bf(e3);
    *(bf16x4*)(Et + (size_t)(mt + i16) * NN + nofs) = ev;  // 8B, n-contiguous
  }
#pragma unroll
  for (int off = 1; off < 16; off <<= 1) {
    s0 += __shfl_xor(s0, off, 64);
    s1 += __shfl_xor(s1, off, 64);
    s2 += __shfl_xor(s2, off, 64);
    s3 += __shfl_xor(s3, off, 64);
  }
  if (i16 == 0) {
    atomicAdd(&sums[nofs + 0], s0);
    atomicAdd(&sums[nofs + 1], s1);
    atomicAdd(&sums[nofs + 2], s2);
    atomicAdd(&sums[nofs + 3], s3);
  }
}

// ---- yT[col][n] = bf16(x[bc][n][t] / sums[n]) via LDS transpose ----
__global__ __launch_bounds__(256) void k_y(const float* __restrict__ x,
                                           const float* __restrict__ sums,
                                           unsigned short* __restrict__ yT) {
  __shared__ float xs[3072];
  const int tid = threadIdx.x;
  const int n0 = blockIdx.x * 256;
  const int bc = blockIdx.y;
  const float* xp = x + (size_t)bc * NN * TT + (size_t)n0 * TT;
#pragma unroll
  for (int j = 0; j < 12; ++j) xs[j * 256 + tid] = xp[j * 256 + tid];
  __syncthreads();
  const float rinv = 1.0f / sums[n0 + tid];
#pragma unroll
  for (int t = 0; t < 12; ++t)
    yT[(size_t)(bc * TT + t) * NN + n0 + tid] = f2bf(xs[tid * 12 + t] * rinv);
}

// ---- main GEMM: part[nc][col][m] = sum_{n in chunk} yT[col][n] * Et[m][n] ----
// grid (64 m-blocks of 128, NSPLIT n-chunks); 4 waves; wave = 6 coltiles x 4 msubs.
// Both operands: direct b128 global loads. Register double-buffer, prefetch-1.
__global__ __launch_bounds__(256, 2) void k_gemm(const unsigned short* __restrict__ Et,
                                                 const unsigned short* __restrict__ yT,
                                                 float* __restrict__ part) {
  const int tid = threadIdx.x;
  const int w = tid >> 6, lane = tid & 63, q = lane >> 4, i16 = lane & 15;
  const int mb = blockIdx.x * 128;
  const int nt0 = blockIdx.y * (NN / NSPLIT);
  const int cw = w & 1, mw = w >> 1;

  const unsigned short* ya[6];
  const unsigned short* eb[4];
#pragma unroll
  for (int c = 0; c < 6; ++c)
    ya[c] = yT + (size_t)((cw * 6 + c) * 16 + i16) * NN + q * 8;
#pragma unroll
  for (int ms = 0; ms < 4; ++ms)
    eb[ms] = Et + (size_t)(mb + (mw * 4 + ms) * 16 + i16) * NN + q * 8;

  f32x4 acc[6][4];
#pragma unroll
  for (int c = 0; c < 6; ++c)
#pragma unroll
    for (int ms = 0; ms < 4; ++ms) acc[c][ms] = (f32x4){0.f, 0.f, 0.f, 0.f};

#define LOAD10(A, B, NT)                                        \
  {                                                             \
    _Pragma("unroll") for (int c = 0; c < 6; ++c)               \
        (A)[c] = *(const bf16x8*)(ya[c] + (NT));                \
    _Pragma("unroll") for (int ms = 0; ms < 4; ++ms)            \
        (B)[ms] = *(const bf16x8*)(eb[ms] + (NT));              \
  }
#define MFMA24(A, B)                                                          \
  {                                                                           \
    _Pragma("unroll") for (int ms = 0; ms < 4; ++ms)                          \
        _Pragma("unroll") for (int c = 0; c < 6; ++c)                         \
            acc[c][ms] = __builtin_amdgcn_mfma_f32_16x16x32_bf16(             \
                a_##A[c], b_##A[ms], acc[c][ms], 0, 0, 0);                    \
  }

  bf16x8 a_0[6], b_0[4], a_1[6], b_1[4];
  LOAD10(a_0, b_0, nt0);
  const int NITER = (NN / NSPLIT) / 64;  // 16 double-steps
  for (int it = 0; it < NITER - 1; ++it) {
    const int base = nt0 + it * 64;
    LOAD10(a_1, b_1, base + 32);
    MFMA24(0, );
    LOAD10(a_0, b_0, base + 64);
    MFMA24(1, );
  }
  LOAD10(a_1, b_1, nt0 + (NITER - 1) * 64 + 32);
  MFMA24(0, );
  MFMA24(1, );
#undef LOAD10
#undef MFMA24

  // epilogue: lane holds col = (cw*6+c)*16 + q*4 + r, m = mb + (mw*4+ms)*16 + i16
  float* pp = part + (size_t)blockIdx.y * 192 * NN;
#pragma unroll
  for (int c = 0; c < 6; ++c)
#pragma unroll
    for (int ms = 0; ms < 4; ++ms) {
      const int colbase = (cw * 6 + c) * 16 + q * 4;
      const int m = mb + (mw * 4 + ms) * 16 + i16;
#pragma unroll
      for (int r = 0; r < 4; ++r)
        pp[(size_t)(colbase + r) * NN + m] = acc[c][ms][r];  // coalesced over i16
    }
}

// ---- reduce NSPLIT partials + transpose to out[bc][m][t] ----
__global__ __launch_bounds__(256) void k_reduce(const float* __restrict__ part,
                                                float* __restrict__ out) {
  __shared__ float os[3072];
  const int tid = threadIdx.x;
  const int m0 = blockIdx.x * 256;
  const int bc = blockIdx.y;
#pragma unroll
  for (int t = 0; t < 12; ++t) {
    const int col = bc * TT + t;
    float s = 0.f;
#pragma unroll
    for (int nc = 0; nc < NSPLIT; ++nc)
      s += part[((size_t)nc * 192 + col) * NN + m0 + tid];
    os[tid * 12 + t] = s;
  }
  __syncthreads();
  float* op = out + (size_t)bc * NN * TT + (size_t)m0 * TT;
#pragma unroll
  for (int j = 0; j < 12; ++j) op[j * 256 + tid] = os[j * 256 + tid];
}

// ======================= fallback (small ws): round-2 fused path =============
__global__ __launch_bounds__(256) void k_stats_f(const unsigned short* __restrict__ t1b,
                                                 const unsigned short* __restrict__ nv2b,
                                                 float* __restrict__ sums) {
  const int tid = threadIdx.x;
  const int w = tid >> 6, lane = tid & 63, q = lane >> 4, i16 = lane & 15;
  const int nbase = blockIdx.x * 64 + w * 16;
  bf16x8 a = *(const bf16x8*)(t1b + (size_t)(nbase + i16) * DD + q * 8);
  const f32x4 z4 = {0.f, 0.f, 0.f, 0.f};
  float s[4] = {0.f, 0.f, 0.f, 0.f};
  const int m0 = blockIdx.y * 2048;
  for (int mt = m0; mt < m0 + 2048; mt += 64) {
#pragma unroll
    for (int u = 0; u < 4; ++u) {
      bf16x8 b = *(const bf16x8*)(nv2b + (size_t)(mt + u * 16 + i16) * DD + q * 8);
      f32x4 d = __builtin_amdgcn_mfma_f32_16x16x32_bf16(a, b, z4, 0, 0, 0);
#pragma unroll
      for (int r = 0; r < 4; ++r) s[r] += __expf(fmaxf(d[r], 0.f));
    }
  }
#pragma unroll
  for (int r = 0; r < 4; ++r)
    for (int off = 1; off < 16; off <<= 1) s[r] += __shfl_xor(s[r], off, 64);
  if (i16 == 0) {
#pragma unroll
    for (int r = 0; r < 4; ++r) atomicAdd(&sums[nbase + q * 4 + r], s[r]);
  }
}

__global__ __launch_bounds__(256, 4) void k_main_f(const unsigned short* __restrict__ t1b,
                                                   const unsigned short* __restrict__ nv2b,
                                                   const unsigned short* __restrict__ yT,
                                                   float* __restrict__ out) {
  const int tid = threadIdx.x;
  const int w = tid >> 6, lane = tid & 63, q = lane >> 4, i16 = lane & 15;
  const int mblock = blockIdx.x * 32;
  const int nt0 = blockIdx.y * 4096;
  __shared__ unsigned short Et[2][32][72];
  bf16x8 b_nv2_0 = *(const bf16x8*)(nv2b + (size_t)(mblock + i16) * DD + q * 8);
  bf16x8 b_nv2_1 = *(const bf16x8*)(nv2b + (size_t)(mblock + 16 + i16) * DD + q * 8);
  f32x4 acc[2][3];
#pragma unroll
  for (int a = 0; a < 2; ++a)
#pragma unroll
    for (int b = 0; b < 3; ++b) acc[a][b] = (f32x4){0.f, 0.f, 0.f, 0.f};
  const f32x4 z4 = {0.f, 0.f, 0.f, 0.f};
  int p = 0;
  for (int nt = nt0; nt < nt0 + 4096; nt += 64, p ^= 1) {
    bf16x8 yfr[3][2];
#pragma unroll
    for (int ctl = 0; ctl < 3; ++ctl) {
      const int ct = w * 3 + ctl;
#pragma unroll
      for (int nc = 0; nc < 2; ++nc)
        yfr[ctl][nc] = *(const bf16x8*)(yT + (size_t)(ct * 16 + i16) * NN + nt + nc * 32 + q * 8);
    }
    bf16x8 a_t1 = *(const bf16x8*)(t1b + (size_t)(nt + w * 16 + i16) * DD + q * 8);
    f32x4 d0 = __builtin_amdgcn_mfma_f32_16x16x32_bf16(a_t1, b_nv2_0, z4, 0, 0, 0);
    f32x4 d1 = __builtin_amdgcn_mfma_f32_16x16x32_bf16(a_t1, b_nv2_1, z4, 0, 0, 0);
    bf16x4 e0, e1;
#pragma unroll
    for (int r = 0; r < 4; ++r) {
      e0[r] = (short)f2bf(__expf(fmaxf(d0[r], 0.f)));
      e1[r] = (short)f2bf(__expf(fmaxf(d1[r], 0.f)));
    }
    *(bf16x4*)&Et[p][i16][w * 16 + q * 4] = e0;
    *(bf16x4*)&Et[p][16 + i16][w * 16 + q * 4] = e1;
    __syncthreads();
    bf16x8 bfr[2][2];
#pragma unroll
    for (int ms = 0; ms < 2; ++ms)
#pragma unroll
      for (int nc = 0; nc < 2; ++nc)
        bfr[ms][nc] = *(const bf16x8*)&Et[p][ms * 16 + i16][nc * 32 + q * 8];
#pragma unroll
    for (int ctl = 0; ctl < 3; ++ctl)
#pragma unroll
      for (int ms = 0; ms < 2; ++ms)
#pragma unroll
        for (int nc = 0; nc < 2; ++nc)
          acc[ms][ctl] = __builtin_amdgcn_mfma_f32_16x16x32_bf16(yfr[ctl][nc], bfr[ms][nc],
                                                                 acc[ms][ctl], 0, 0, 0);
  }
#pragma unroll
  for (int ms = 0; ms < 2; ++ms)
#pragma unroll
    for (int ctl = 0; ctl < 3; ++ctl) {
      const int colbase = (w * 3 + ctl) * 16 + q * 4;
      const int m = mblock + ms * 16 + i16;
#pragma unroll
      for (int r = 0; r < 4; ++r) {
        const int col = colbase + r;
        const int bc = col / TT, t = col - bc * TT;
        atomicAdd(&out[((size_t)bc * NN + m) * TT + t], acc[ms][ctl][r]);
      }
    }
}

extern "C" void kernel_launch(void* const* d_in, const int* in_sizes, int n_in,
                              void* d_out, int out_size, void* d_ws, size_t ws_size,
                              hipStream_t stream) {
  const float* x = (const float*)d_in[0];
  const float* nv1 = (const float*)d_in[1];
  const float* nv2 = (const float*)d_in[2];
  const float* tv = (const float*)d_in[3];
  const float* kk = (const float*)d_in[4];
  const int* tind = (const int*)d_in[5];
  float* out = (float*)d_out;

  char* ws = (char*)d_ws;
  unsigned short* t1b  = (unsigned short*)(ws);            //  524288 B
  unsigned short* nv2b = (unsigned short*)(ws + 524288);   //  524288 B
  float* sums          = (float*)(ws + 1048576);           //   32768 B
  unsigned short* yT   = (unsigned short*)(ws + 1081344);  // 3145728 B -> 4227072
  unsigned short* Et   = (unsigned short*)(ws + 4227072);  // 134217728 B -> 138444800
  float* part          = (float*)(ws + 138444800);         // 50331648 B -> 188776448

  const size_t REQ = 188776448;

  hipMemsetAsync(sums, 0, NN * sizeof(float), stream);
  k_prep<<<64, 256, 0, stream>>>(nv1, nv2, tv, kk, tind, t1b, nv2b);

  if (ws_size >= REQ) {
    k_passA<<<dim3(128, 4), 256, 0, stream>>>(t1b, nv2b, Et, sums);
    k_y<<<dim3(32, 16), 256, 0, stream>>>(x, sums, yT);
    k_gemm<<<dim3(64, NSPLIT), 256, 0, stream>>>(Et, yT, part);
    k_reduce<<<dim3(32, 16), 256, 0, stream>>>(part, out);
  } else {
    hipMemsetAsync(d_out, 0, (size_t)out_size * sizeof(float), stream);
    k_stats_f<<<dim3(128, 4), 256, 0, stream>>>(t1b, nv2b, sums);
    k_y<<<dim3(32, 16), 256, 0, stream>>>(x, sums, yT);
    k_main_f<<<dim3(256, 2), 256, 0, stream>>>(t1b, nv2b, yT, out);
  }
}